// Round 9
// baseline (384.966 us; speedup 1.0000x reference)
//
#include <hip/hip_runtime.h>
#include <hip/hip_bf16.h>

typedef unsigned short u16;
typedef __attribute__((ext_vector_type(8))) short bf16x8;   // 8 bf16 = 4 VGPRs
typedef __attribute__((ext_vector_type(4))) float f32x4;

#define B_   2
#define T_   2048
#define DM   2048
#define NH   16
#define DH   128
#define NQKV 6144

__device__ __forceinline__ u16 f2bf(float f) {
  __hip_bfloat16 h = __float2bfloat16(f);
  u16 u; __builtin_memcpy(&u, &h, 2); return u;
}
__device__ __forceinline__ float bf2f(u16 u) {
  __hip_bfloat16 h; __builtin_memcpy(&h, &u, 2); return __bfloat162float(h);
}
// async global->LDS, 16B per lane; lds dest must be wave-uniform base (HW adds lane*16)
__device__ __forceinline__ void gl_lds16(const void* g, void* l) {
  __builtin_amdgcn_global_load_lds(
      (__attribute__((address_space(1))) unsigned int*)g,
      (__attribute__((address_space(3))) unsigned int*)l, 16, 0, 0);
}
__device__ __forceinline__ f32x4 MFMA(bf16x8 a, bf16x8 b, f32x4 c) {
  return __builtin_amdgcn_mfma_f32_16x16x32_bf16(a, b, c, 0, 0, 0);
}

// ------------- fp32 -> bf16 cast, all three inputs in one launch ----------
__global__ __launch_bounds__(256) void cast3(const float* __restrict__ x,
                                             u16* __restrict__ xb,
                                             const float* __restrict__ wq,
                                             u16* __restrict__ wqb,
                                             const float* __restrict__ wo,
                                             u16* __restrict__ wob) {
  const int n1 = B_ * T_ * DM / 4, n2 = NQKV * DM / 4, n3 = DM * DM / 4;
  int i = blockIdx.x * 256 + threadIdx.x;
  const float4* src; ushort4* dst; int k;
  if (i < n1)           { src = (const float4*)x;  dst = (ushort4*)xb;  k = i; }
  else if (i < n1 + n2) { src = (const float4*)wq; dst = (ushort4*)wqb; k = i - n1; }
  else if (i < n1 + n2 + n3) { src = (const float4*)wo; dst = (ushort4*)wob; k = i - n1 - n2; }
  else return;
  float4 v = src[k];
  ushort4 o;
  o.x = f2bf(v.x); o.y = f2bf(v.y); o.z = f2bf(v.z); o.w = f2bf(v.w);
  dst[k] = o;
}

// ---------------- RoPE cos/sin table: tab[t*64+i] = (cos, sin) ----------
// Isolates libm sincosf in a low-pressure kernel (round-5 post-mortem: 128
// sincosf CALL sites in the fused GEMM epilogue => ~200MB scratch traffic).
__global__ __launch_bounds__(256) void rope_tab(float2* __restrict__ tab) {
  int idx = blockIdx.x * 256 + threadIdx.x;   // t*64 + i
  if (idx >= T_ * 64) return;
  int t = idx >> 6, i = idx & 63;
  float freq = __expf(-9.210340371976184f * (float)i / 64.0f);
  float sn, cs;
  sincosf((float)t * freq, &sn, &cs);
  tab[idx] = make_float2(cs, sn);
}

// ========== GEMM1 + fused RoPE/reorder (table-based), direct stores ========
// qkv = x (4096x2048) * Wqkv^T (6144x2048). Epilogue ropes Q/K via the
// precomputed table and writes (bh,t,d) bf16 (Q pre-scaled 1/sqrt(128));
// V written transposed (bh,d,t) as ushort4. (Verified round 6: WRITE 71MB,
// FETCH 102MB, 132us.) K-loop: one barrier per phase; region = [lgkmcnt(0);
// MFMA q; sched_barrier; ds_read frags for q+1; stage; barrier]; vmcnt(4)
// gate @ph2; 6 loads in flight after each ph3.
#define G1_M 4096
#define G1_N 6144
#define G1_K 2048

#define MFMA_Q(AQ, M0)                                                        \
  _Pragma("unroll") for (int e_ = 0; e_ < 2; ++e_)                            \
  _Pragma("unroll") for (int n_ = 0; n_ < 4; ++n_)                            \
  _Pragma("unroll") for (int kb_ = 0; kb_ < 2; ++kb_)                         \
    acc[(M0) + e_][n_] = MFMA(AQ[e_][kb_], bfr[n_][kb_], acc[(M0) + e_][n_])

#define BARRIER() asm volatile("s_barrier" ::: "memory")
#define LGKM0()                                                               \
  do {                                                                        \
    asm volatile("s_waitcnt lgkmcnt(0)" ::: "memory");                        \
    __builtin_amdgcn_sched_barrier(0);                                        \
  } while (0)
#define SBAR() __builtin_amdgcn_sched_barrier(0)

__global__ __launch_bounds__(512, 2) void gemm1_8ph(const u16* __restrict__ A,
                                                    const u16* __restrict__ Bm,
                                                    const float2* __restrict__ tab,
                                                    u16* __restrict__ Qo,
                                                    u16* __restrict__ Ko,
                                                    u16* __restrict__ Vt) {
  __shared__ alignas(16) u16 As[2][256 * 64];
  __shared__ alignas(16) u16 Bs[2][256 * 64];
  const int tid = threadIdx.x;
  const int w = tid >> 6, lane = tid & 63;
  const int lrow = lane & 15, quad = lane >> 4;
  const long tileM = (long)blockIdx.y * 256, tileN = (long)blockIdx.x * 256;
  const int wm = (w >> 2) * 128, wn = (w & 3) * 64;

  const int sw8 = w * 8;
  const int srowL = lane >> 3;
  const int schunk = ((lane & 7) ^ srowL) * 8;
  const u16* Ag0 = A + (tileM + sw8 + srowL) * (long)G1_K + schunk;
  const u16* Bg0 = Bm + (tileN + sw8 + srowL) * (long)G1_K + schunk;

  auto stgA = [&](int tt, int h) {
    const int b = tt & 1;
    gl_lds16(Ag0 + (size_t)(h * 128) * G1_K + tt * 64,
             &As[b][(h * 128 + sw8) * 64]);
    gl_lds16(Ag0 + (size_t)(h * 128 + 64) * G1_K + tt * 64,
             &As[b][(h * 128 + 64 + sw8) * 64]);
  };
  auto stgB = [&](int tt, int h) {
    const int b = tt & 1;
    gl_lds16(Bg0 + (size_t)(h * 128) * G1_K + tt * 64,
             &Bs[b][(h * 128 + sw8) * 64]);
    gl_lds16(Bg0 + (size_t)(h * 128 + 64) * G1_K + tt * 64,
             &Bs[b][(h * 128 + 64 + sw8) * 64]);
  };

  const int aBase = (wm + lrow) * 64;
  const int bBase = (wn + lrow) * 64;
  const int slot[2] = { (quad ^ (lrow & 7)) * 8, ((4 + quad) ^ (lrow & 7)) * 8 };

  f32x4 acc[8][4] = {};
  bf16x8 bfr[4][2];          // B resident for current tile
  bf16x8 aCur[2][2], aNxt[2][2];

  // prologue: t0 complete + t1's {B0,B1,A0} in flight; vmcnt(6) drains t0.
  stgA(0, 0); stgA(0, 1); stgB(0, 0); stgB(0, 1);
  stgB(1, 0); stgB(1, 1); stgA(1, 0);
  asm volatile("s_waitcnt vmcnt(6)" ::: "memory");
  BARRIER();
  // pre-read q0 frags of t0: B(all 8) + A01
#pragma unroll
  for (int ni = 0; ni < 4; ++ni)
#pragma unroll
    for (int kb = 0; kb < 2; ++kb)
      bfr[ni][kb] = *(const bf16x8*)(Bs[0] + bBase + ni * 1024 + slot[kb]);
#pragma unroll
  for (int e = 0; e < 2; ++e)
#pragma unroll
    for (int kb = 0; kb < 2; ++kb)
      aCur[e][kb] = *(const bf16x8*)(As[0] + aBase + e * 1024 + slot[kb]);

#pragma unroll 1
  for (int t = 0; t < 32; ++t) {
    const u16* AsC = As[t & 1];
    // ---- region ph0: MFMA q0; read A23; stage A(t+1,h1)
    LGKM0();
    __builtin_amdgcn_s_setprio(1);
    MFMA_Q(aCur, 0);
    __builtin_amdgcn_s_setprio(0);
    SBAR();
#pragma unroll
    for (int e = 0; e < 2; ++e)
#pragma unroll
      for (int kb = 0; kb < 2; ++kb)
        aNxt[e][kb] = *(const bf16x8*)(AsC + aBase + (2 + e) * 1024 + slot[kb]);
    if (t + 1 < 32) stgA(t + 1, 1);
    BARRIER();
    // ---- region ph1: MFMA q1; read A45; stage B(t+2,h0)
    LGKM0();
    __builtin_amdgcn_s_setprio(1);
    MFMA_Q(aNxt, 2);
    __builtin_amdgcn_s_setprio(0);
    SBAR();
#pragma unroll
    for (int e = 0; e < 2; ++e)
#pragma unroll
      for (int kb = 0; kb < 2; ++kb)
        aCur[e][kb] = *(const bf16x8*)(AsC + aBase + (4 + e) * 1024 + slot[kb]);
    if (t + 2 < 32) stgB(t + 2, 0);
    BARRIER();
    // ---- region ph2: MFMA q2; read A67; stage B(t+2,h1); vmcnt gate for t+1
    LGKM0();
    __builtin_amdgcn_s_setprio(1);
    MFMA_Q(aCur, 4);
    __builtin_amdgcn_s_setprio(0);
    SBAR();
#pragma unroll
    for (int e = 0; e < 2; ++e)
#pragma unroll
      for (int kb = 0; kb < 2; ++kb)
        aNxt[e][kb] = *(const bf16x8*)(AsC + aBase + (6 + e) * 1024 + slot[kb]);
    if (t + 2 < 32) stgB(t + 2, 1);
    if (t < 30) { asm volatile("s_waitcnt vmcnt(4)" ::: "memory"); }
    else       { asm volatile("s_waitcnt vmcnt(0)" ::: "memory"); }
    BARRIER();
    // ---- region ph3: MFMA q3; read B(t+1)+A01(t+1); stage A(t+2,h0)
    LGKM0();
    __builtin_amdgcn_s_setprio(1);
    MFMA_Q(aNxt, 6);
    __builtin_amdgcn_s_setprio(0);
    SBAR();
    if (t + 1 < 32) {
      const u16* AsN = As[(t + 1) & 1];
      const u16* BsN = Bs[(t + 1) & 1];
#pragma unroll
      for (int ni = 0; ni < 4; ++ni)
#pragma unroll
        for (int kb = 0; kb < 2; ++kb)
          bfr[ni][kb] = *(const bf16x8*)(BsN + bBase + ni * 1024 + slot[kb]);
#pragma unroll
      for (int e = 0; e < 2; ++e)
#pragma unroll
        for (int kb = 0; kb < 2; ++kb)
          aCur[e][kb] = *(const bf16x8*)(AsN + aBase + e * 1024 + slot[kb]);
    }
    if (t + 2 < 32) stgA(t + 2, 0);
    BARRIER();
  }

  // ---------- fused epilogue: RoPE (table) + reorder, direct stores ----------
  const long crow = tileM + wm + quad * 4;
  const long ccol = tileN + wn + lrow;
  const int sec = (int)(tileN >> 11);           // 0=Q, 1=K, 2=V (uniform/block)
  const int bI = (int)(tileM >> 11);
  const int tG0 = (int)(tileM & 2047);
  if (sec < 2) {
    u16* dst = sec == 0 ? Qo : Ko;
    const float scale = sec == 0 ? 0.08838834764831845f : 1.0f;  // 1/sqrt(128)
#pragma unroll
    for (int ni = 0; ni < 4; ++ni) {
      const int col = (int)((ccol + ni * 16) & 2047);
      const int h = col >> 7, d = col & 127;
      const int i = d >> 1;                     // rope pair index
      const float2* tcol = tab + i;             // + t*64 per row
#pragma unroll
      for (int mi = 0; mi < 8; ++mi) {
        const int rowL = wm + mi * 16 + quad * 4;      // local, +r below
#pragma unroll
        for (int r = 0; r < 4; ++r) {
          const int tt = tG0 + rowL + r;
          float x = acc[mi][ni][r];
          float p = __shfl_xor(x, 1);           // partner col d^1, same row
          float2 sc = tcol[(size_t)tt * 64];    // (cos, sin), L2-hot
          float o = (x * sc.x + ((d & 1) ? p : -p) * sc.y) * scale;
          dst[(((size_t)(bI * 16 + h)) * T_ + tt) * DH + d] = f2bf(o);
        }
      }
    }
  } else {
    // V: no rope; write transposed (bh, d, t). acc[mi][ni][0..3] = 4 consec t.
#pragma unroll
    for (int ni = 0; ni < 4; ++ni) {
      const int col = (int)((ccol + ni * 16) & 2047);
      const int h = col >> 7, d = col & 127;
#pragma unroll
      for (int mi = 0; mi < 8; ++mi) {
        const int t0 = tG0 + wm + mi * 16 + quad * 4;  // 4-aligned
        ushort4 v4;
        v4.x = f2bf(acc[mi][ni][0]);
        v4.y = f2bf(acc[mi][ni][1]);
        v4.z = f2bf(acc[mi][ni][2]);
        v4.w = f2bf(acc[mi][ni][3]);
        *(ushort4*)(Vt + (((size_t)(bI * 16 + h)) * DH + d) * (size_t)T_ + t0) = v4;
      }
    }
  }
}

// ---------------- C = A (MxK) * B^T (NxK), bf16 in, bf16 or f32 out ----
// (GEMM2: N=2048 -> 512 blocks at 128^2; multiple blocks/CU resident (32KB
// LDS, 92 VGPR) so TLP hides the per-iter vmcnt(0) drain — no pipeline needed.)
__global__ __launch_bounds__(256) void gemm_bt(const u16* __restrict__ A,
                                               const u16* __restrict__ Bm,
                                               void* __restrict__ Cp,
                                               int M, int N, int K, int out_f32) {
  __shared__ u16 As[128 * 64];
  __shared__ u16 Bs[128 * 64];
  const int tid  = threadIdx.x;
  const int wave = tid >> 6, lane = tid & 63;
  const int lrow = lane & 15, quad = lane >> 4;
  const long tileM = (long)blockIdx.y * 128, tileN = (long)blockIdx.x * 128;
  const int wm = (wave >> 1) * 64, wn = (wave & 1) * 64;
  const int sRowIn = lane >> 3;
  const int sChunk = (lane & 7) ^ sRowIn;
  const int sRow0  = wave * 32 + sRowIn;
  const u16* Ag = A + (tileM + sRow0) * (long)K + sChunk * 8;
  const u16* Bg = Bm + (tileN + sRow0) * (long)K + sChunk * 8;
  u16* AsW = As + wave * 2048;
  u16* BsW = Bs + wave * 2048;
  f32x4 acc[4][4] = {};
  for (int kt = 0; kt < K; kt += 64) {
#pragma unroll
    for (int i = 0; i < 4; ++i)
      gl_lds16(Ag + kt + (size_t)i * 8 * K, AsW + i * 512);
#pragma unroll
    for (int i = 0; i < 4; ++i)
      gl_lds16(Bg + kt + (size_t)i * 8 * K, BsW + i * 512);
    __syncthreads();
#pragma unroll
    for (int kb = 0; kb < 2; ++kb) {
      const int slot8 = (((kb * 4 + quad) ^ (lrow & 7)) * 8);
      bf16x8 af[4], bfr[4];
#pragma unroll
      for (int i = 0; i < 4; ++i)
        af[i]  = *(const bf16x8*)(As + (wm + i * 16 + lrow) * 64 + slot8);
#pragma unroll
      for (int i = 0; i < 4; ++i)
        bfr[i] = *(const bf16x8*)(Bs + (wn + i * 16 + lrow) * 64 + slot8);
#pragma unroll
      for (int mi = 0; mi < 4; ++mi)
#pragma unroll
        for (int ni = 0; ni < 4; ++ni)
          acc[mi][ni] = MFMA(af[mi], bfr[ni], acc[mi][ni]);
    }
    __syncthreads();
  }
  const long crow = tileM + wm + quad * 4;
  const long ccol = tileN + wn + lrow;
  if (out_f32) {
    float* C = (float*)Cp;
#pragma unroll
    for (int mi = 0; mi < 4; ++mi)
#pragma unroll
      for (int ni = 0; ni < 4; ++ni)
#pragma unroll
        for (int r = 0; r < 4; ++r)
          C[(crow + mi * 16 + r) * (long)N + (ccol + ni * 16)] = acc[mi][ni][r];
  } else {
    u16* C = (u16*)Cp;
#pragma unroll
    for (int mi = 0; mi < 4; ++mi)
#pragma unroll
      for (int ni = 0; ni < 4; ++ni)
#pragma unroll
        for (int r = 0; r < 4; ++r)
          C[(crow + mi * 16 + r) * (long)N + (ccol + ni * 16)] = f2bf(acc[mi][ni][r]);
  }
}

// -------- causal flash attention (4-wave, 32 q-rows/wave, dbuf K/V) --------
// grid (8, B*NH); block 256 = 4 waves; q-tile 128 rows, wave owns 32 (2
// m-frags). Round-8 post-mortem: attn is LDS-BANDWIDTH bound — 8 waves each
// re-read the same K/V frags for one 16-row A-frag (272KB/tile through one
// CU's LDS, 1 MFMA per 1KB read). Here each kf/vf register read feeds 2
// MFMAs: per-tile block traffic 272 -> 144KB. K/V double-buffer kept
// (counted vmcnt(8), raw s_barrier, lgkmcnt(0) before restage barrier).
// Pairing: qtH = 15-p, qtL = p -> 34 K-iters total, uniform across blocks.
// No-max softmax: scores bounded by construction; p = exp(s) fp32-safe.
__global__ __launch_bounds__(256) void attn_flash(const u16* __restrict__ Q,
                                                  const u16* __restrict__ K,
                                                  const u16* __restrict__ Vt,
                                                  u16* __restrict__ AO) {
  __shared__ u16 Kl[2][64 * 128];  // (key t, d), swizzle key = row&15
  __shared__ u16 Vl[2][128 * 64];  // (d, key t), swizzle key = row&7
  __shared__ u16 Pl[4 * 32 * 64];  // per-wave P staging (32 rows)
  const int pairIdx = blockIdx.x;              // 0..7
  const int bh = blockIdx.y;
  const int b = bh >> 4, h = bh & 15;
  const int tid = threadIdx.x;
  const int wave = tid >> 6, lane = tid & 63;  // wave 0..3
  const int lrow = lane & 15, quad = lane >> 4;
  const u16* Qb = Q + (size_t)bh * T_ * DH;
  const u16* Kb = K + (size_t)bh * T_ * DH;
  const u16* Vb = Vt + (size_t)bh * DH * T_;

  // staging per wave: K rows [wave*16, +16) (4 issues x 4 rows), V d-rows
  // [wave*32, +32) (4 issues x 8 rows). 8 gl_lds per wave per tile.
  const int kRowIn = lane >> 4;                 // 0..3
  const int vRowIn = lane >> 3;                 // 0..7
  const int vChunk = (lane & 7) ^ vRowIn;       // key = row&7 (i*8 drops out)
  u16* PlW = Pl + wave * 2048;

  auto stageKV = [&](int j, int buf) {
#pragma unroll
    for (int i = 0; i < 4; ++i) {
      int krow = wave * 16 + i * 4 + kRowIn;
      int kch = (lane & 15) ^ (krow & 15);      // staging key = row&15
      gl_lds16(Kb + (size_t)(j * 64 + krow) * DH + kch * 8,
               Kl[buf] + wave * 2048 + i * 512);
    }
#pragma unroll
    for (int i = 0; i < 4; ++i) {
      int vd = wave * 32 + i * 8 + vRowIn;
      gl_lds16(Vb + (size_t)vd * T_ + j * 64 + vChunk * 8,
               Vl[buf] + wave * 2048 + i * 512);
    }
  };

  for (int pass = 0; pass < 2; ++pass) {
    const int qt = pass == 0 ? (15 - pairIdx) : pairIdx;   // 128-row q-tile
    const int qbase = qt * 128;
    const int nkt = 2 * qt + 2;                 // K-tiles of 64

    bf16x8 qf[2][4];
#pragma unroll
    for (int m = 0; m < 2; ++m) {
      const u16* qrow =
          Qb + (size_t)(qbase + wave * 32 + m * 16 + lrow) * DH + quad * 8;
#pragma unroll
      for (int kc = 0; kc < 4; ++kc) qf[m][kc] = *(const bf16x8*)(qrow + kc * 32);
    }
    f32x4 o[2][8] = {};
    float lsum[2][4] = {};

    stageKV(0, 0);                              // prologue prefetch

    for (int j = 0; j < nkt; ++j) {
      const int cb = j & 1;
      if (j + 1 < nkt) {
        stageKV(j + 1, cb ^ 1);                 // issue next tile early
        asm volatile("s_waitcnt vmcnt(8)" ::: "memory");  // drain tile j only
      } else {
        asm volatile("s_waitcnt vmcnt(0)" ::: "memory");
      }
      BARRIER();                                // buf[cb] ready for all waves

      const u16* KlC = Kl[cb];
      const u16* VlC = Vl[cb];
      f32x4 s[2][4] = {};
#pragma unroll
      for (int kc = 0; kc < 4; ++kc)
#pragma unroll
        for (int ns = 0; ns < 4; ++ns) {
          bf16x8 kf = *(const bf16x8*)(KlC + (ns * 16 + lrow) * 128 +
                                       (((kc * 4 + quad) ^ lrow) * 8));
          s[0][ns] = MFMA(qf[0][kc], kf, s[0][ns]);   // kf feeds BOTH m-frags
          s[1][ns] = MFMA(qf[1][kc], kf, s[1][ns]);
        }
      if (j >= 2 * qt) {  // diagonal K-tiles: mask local col > local row
        const int jl = (j - 2 * qt) * 64;
#pragma unroll
        for (int m = 0; m < 2; ++m)
#pragma unroll
          for (int ns = 0; ns < 4; ++ns)
#pragma unroll
            for (int r = 0; r < 4; ++r)
              if (jl + ns * 16 + lrow > wave * 32 + m * 16 + quad * 4 + r)
                s[m][ns][r] = -__builtin_inff();
      }
#pragma unroll
      for (int m = 0; m < 2; ++m)
#pragma unroll
        for (int r = 0; r < 4; ++r) {
          const int prow = m * 16 + quad * 4 + r;
#pragma unroll
          for (int ns = 0; ns < 4; ++ns) {
            float p = __expf(s[m][ns][r]);      // exp(-inf) = 0 handles mask
            PlW[prow * 64 + (((ns * 2 + (lrow >> 3)) ^ (prow & 7)) * 8) +
                (lrow & 7)] = f2bf(p);
            lsum[m][r] += p;
          }
        }
      // no barrier: Pl is per-wave; same-wave LDS write->read ordered by lgkmcnt

#pragma unroll
      for (int kc = 0; kc < 2; ++kc) {
        const int sl = ((kc * 4 + quad) ^ (lrow & 7)) * 8;
        bf16x8 pf0 = *(const bf16x8*)(PlW + lrow * 64 + sl);
        bf16x8 pf1 = *(const bf16x8*)(PlW + (16 + lrow) * 64 + sl);
#pragma unroll
        for (int os = 0; os < 8; ++os) {
          bf16x8 vf = *(const bf16x8*)(VlC + (os * 16 + lrow) * 64 + sl);
          o[0][os] = MFMA(pf0, vf, o[0][os]);   // vf feeds BOTH m-frags
          o[1][os] = MFMA(pf1, vf, o[1][os]);
        }
      }
      asm volatile("s_waitcnt lgkmcnt(0)" ::: "memory");  // reads of buf done
      BARRIER();                                // buf[cb] free for restage
    }
#pragma unroll
    for (int m = 0; m < 2; ++m) {
#pragma unroll
      for (int r = 0; r < 4; ++r) {
        lsum[m][r] += __shfl_xor(lsum[m][r], 1, 16);
        lsum[m][r] += __shfl_xor(lsum[m][r], 2, 16);
        lsum[m][r] += __shfl_xor(lsum[m][r], 4, 16);
        lsum[m][r] += __shfl_xor(lsum[m][r], 8, 16);
      }
#pragma unroll
      for (int r = 0; r < 4; ++r) {
        float inv = 1.0f / lsum[m][r];
        const size_t row =
            (size_t)b * T_ + qbase + wave * 32 + m * 16 + quad * 4 + r;
        u16* dst = AO + row * DM + h * DH;
#pragma unroll
        for (int os = 0; os < 8; ++os)
          dst[os * 16 + lrow] = f2bf(o[m][os][r] * inv);
      }
    }
  }
}

extern "C" void kernel_launch(void* const* d_in, const int* in_sizes, int n_in,
                              void* d_out, int out_size, void* d_ws, size_t ws_size,
                              hipStream_t stream) {
  const float* x    = (const float*)d_in[0];
  const float* Wqkv = (const float*)d_in[1];
  const float* WO   = (const float*)d_in[2];
  char* ws = (char*)d_ws;
  size_t off = 0;
  u16* xb   = (u16*)(ws + off); off += (size_t)B_ * T_ * DM * 2;        // 16.8MB
  u16* wqb  = (u16*)(ws + off); off += (size_t)NQKV * DM * 2;           // 25.2MB
  u16* wob  = (u16*)(ws + off); off += (size_t)DM * DM * 2;             // 8.4MB
  u16* Qb   = (u16*)(ws + off); off += (size_t)B_ * NH * T_ * DH * 2;   // 16.8MB
  u16* Kb   = (u16*)(ws + off); off += (size_t)B_ * NH * T_ * DH * 2;
  u16* Vtb  = (u16*)(ws + off); off += (size_t)B_ * NH * T_ * DH * 2;
  float2* tabp = (float2*)(ws + off); off += (size_t)T_ * 64 * 8;       // 1MB
  u16* AO   = xb;  // alias: xb dead after GEMM1, AO written after

  rope_tab<<<(T_ * 64 + 255) / 256, 256, 0, stream>>>(tabp);
  const int nc = (B_ * T_ * DM + NQKV * DM + DM * DM) / 4;
  cast3<<<(nc + 255) / 256, 256, 0, stream>>>(x, xb, Wqkv, wqb, WO, wob);

  gemm1_8ph<<<dim3(G1_N / 256, G1_M / 256), 512, 0, stream>>>(xb, wqb, tabp,
                                                              Qb, Kb, Vtb);

  attn_flash<<<dim3(8, B_ * NH), 256, 0, stream>>>(Qb, Kb, Vtb, AO);

  gemm_bt<<<dim3(DM / 128, B_ * T_ / 128), 256, 0, stream>>>(
      AO, wob, d_out, B_ * T_, DM, DM, 1);
}

// Round 10
// 355.490 us; speedup vs baseline: 1.0829x; 1.0829x over previous
//
#include <hip/hip_runtime.h>
#include <hip/hip_bf16.h>

typedef unsigned short u16;
typedef __attribute__((ext_vector_type(8))) short bf16x8;   // 8 bf16 = 4 VGPRs
typedef __attribute__((ext_vector_type(4))) float f32x4;

#define B_   2
#define T_   2048
#define DM   2048
#define NH   16
#define DH   128
#define NQKV 6144

__device__ __forceinline__ u16 f2bf(float f) {
  __hip_bfloat16 h = __float2bfloat16(f);
  u16 u; __builtin_memcpy(&u, &h, 2); return u;
}
__device__ __forceinline__ float bf2f(u16 u) {
  __hip_bfloat16 h; __builtin_memcpy(&h, &u, 2); return __bfloat162float(h);
}
// async global->LDS, 16B per lane; lds dest must be wave-uniform base (HW adds lane*16)
__device__ __forceinline__ void gl_lds16(const void* g, void* l) {
  __builtin_amdgcn_global_load_lds(
      (__attribute__((address_space(1))) unsigned int*)g,
      (__attribute__((address_space(3))) unsigned int*)l, 16, 0, 0);
}
__device__ __forceinline__ f32x4 MFMA(bf16x8 a, bf16x8 b, f32x4 c) {
  return __builtin_amdgcn_mfma_f32_16x16x32_bf16(a, b, c, 0, 0, 0);
}

// ----- fp32 -> bf16 cast (all three inputs) + RoPE table, one launch -------
// Table part: tab[t*64+i] = (cos, sin) of t*10000^(-i/64); first 131072
// threads also emit one table entry (libm sincosf isolated at low register
// pressure — round-5 post-mortem: sincosf calls inside the fused GEMM
// epilogue caused ~200MB of scratch/spill HBM traffic).
__global__ __launch_bounds__(256) void cast3(const float* __restrict__ x,
                                             u16* __restrict__ xb,
                                             const float* __restrict__ wq,
                                             u16* __restrict__ wqb,
                                             const float* __restrict__ wo,
                                             u16* __restrict__ wob,
                                             float2* __restrict__ tab) {
  const int n1 = B_ * T_ * DM / 4, n2 = NQKV * DM / 4, n3 = DM * DM / 4;
  int i = blockIdx.x * 256 + threadIdx.x;
  if (i < T_ * 64) {
    int t = i >> 6, fi = i & 63;
    float freq = __expf(-9.210340371976184f * (float)fi / 64.0f);
    float sn, cs;
    sincosf((float)t * freq, &sn, &cs);
    tab[i] = make_float2(cs, sn);
  }
  const float4* src; ushort4* dst; int k;
  if (i < n1)           { src = (const float4*)x;  dst = (ushort4*)xb;  k = i; }
  else if (i < n1 + n2) { src = (const float4*)wq; dst = (ushort4*)wqb; k = i - n1; }
  else if (i < n1 + n2 + n3) { src = (const float4*)wo; dst = (ushort4*)wob; k = i - n1 - n2; }
  else return;
  float4 v = src[k];
  ushort4 o;
  o.x = f2bf(v.x); o.y = f2bf(v.y); o.z = f2bf(v.z); o.w = f2bf(v.w);
  dst[k] = o;
}

// ========== GEMM1 + fused RoPE/reorder (table-based), direct stores ========
// qkv = x (4096x2048) * Wqkv^T (6144x2048). Epilogue ropes Q/K via the
// precomputed table and writes (bh,t,d) bf16 (Q pre-scaled 1/sqrt(128));
// V written transposed (bh,d,t) as ushort4. (Verified round 6: WRITE 71MB,
// FETCH 102MB, 132us.) K-loop: one barrier per phase; region = [lgkmcnt(0);
// MFMA q; sched_barrier; ds_read frags for q+1; stage; barrier]; vmcnt(4)
// gate @ph2; 6 loads in flight after each ph3. FROZEN since round 6.
#define G1_M 4096
#define G1_N 6144
#define G1_K 2048

#define MFMA_Q(AQ, M0)                                                        \
  _Pragma("unroll") for (int e_ = 0; e_ < 2; ++e_)                            \
  _Pragma("unroll") for (int n_ = 0; n_ < 4; ++n_)                            \
  _Pragma("unroll") for (int kb_ = 0; kb_ < 2; ++kb_)                         \
    acc[(M0) + e_][n_] = MFMA(AQ[e_][kb_], bfr[n_][kb_], acc[(M0) + e_][n_])

#define BARRIER() asm volatile("s_barrier" ::: "memory")
#define LGKM0()                                                               \
  do {                                                                        \
    asm volatile("s_waitcnt lgkmcnt(0)" ::: "memory");                        \
    __builtin_amdgcn_sched_barrier(0);                                        \
  } while (0)
#define SBAR() __builtin_amdgcn_sched_barrier(0)

__global__ __launch_bounds__(512, 2) void gemm1_8ph(const u16* __restrict__ A,
                                                    const u16* __restrict__ Bm,
                                                    const float2* __restrict__ tab,
                                                    u16* __restrict__ Qo,
                                                    u16* __restrict__ Ko,
                                                    u16* __restrict__ Vt) {
  __shared__ alignas(16) u16 As[2][256 * 64];
  __shared__ alignas(16) u16 Bs[2][256 * 64];
  const int tid = threadIdx.x;
  const int w = tid >> 6, lane = tid & 63;
  const int lrow = lane & 15, quad = lane >> 4;
  const long tileM = (long)blockIdx.y * 256, tileN = (long)blockIdx.x * 256;
  const int wm = (w >> 2) * 128, wn = (w & 3) * 64;

  const int sw8 = w * 8;
  const int srowL = lane >> 3;
  const int schunk = ((lane & 7) ^ srowL) * 8;
  const u16* Ag0 = A + (tileM + sw8 + srowL) * (long)G1_K + schunk;
  const u16* Bg0 = Bm + (tileN + sw8 + srowL) * (long)G1_K + schunk;

  auto stgA = [&](int tt, int h) {
    const int b = tt & 1;
    gl_lds16(Ag0 + (size_t)(h * 128) * G1_K + tt * 64,
             &As[b][(h * 128 + sw8) * 64]);
    gl_lds16(Ag0 + (size_t)(h * 128 + 64) * G1_K + tt * 64,
             &As[b][(h * 128 + 64 + sw8) * 64]);
  };
  auto stgB = [&](int tt, int h) {
    const int b = tt & 1;
    gl_lds16(Bg0 + (size_t)(h * 128) * G1_K + tt * 64,
             &Bs[b][(h * 128 + sw8) * 64]);
    gl_lds16(Bg0 + (size_t)(h * 128 + 64) * G1_K + tt * 64,
             &Bs[b][(h * 128 + 64 + sw8) * 64]);
  };

  const int aBase = (wm + lrow) * 64;
  const int bBase = (wn + lrow) * 64;
  const int slot[2] = { (quad ^ (lrow & 7)) * 8, ((4 + quad) ^ (lrow & 7)) * 8 };

  f32x4 acc[8][4] = {};
  bf16x8 bfr[4][2];          // B resident for current tile
  bf16x8 aCur[2][2], aNxt[2][2];

  // prologue: t0 complete + t1's {B0,B1,A0} in flight; vmcnt(6) drains t0.
  stgA(0, 0); stgA(0, 1); stgB(0, 0); stgB(0, 1);
  stgB(1, 0); stgB(1, 1); stgA(1, 0);
  asm volatile("s_waitcnt vmcnt(6)" ::: "memory");
  BARRIER();
  // pre-read q0 frags of t0: B(all 8) + A01
#pragma unroll
  for (int ni = 0; ni < 4; ++ni)
#pragma unroll
    for (int kb = 0; kb < 2; ++kb)
      bfr[ni][kb] = *(const bf16x8*)(Bs[0] + bBase + ni * 1024 + slot[kb]);
#pragma unroll
  for (int e = 0; e < 2; ++e)
#pragma unroll
    for (int kb = 0; kb < 2; ++kb)
      aCur[e][kb] = *(const bf16x8*)(As[0] + aBase + e * 1024 + slot[kb]);

#pragma unroll 1
  for (int t = 0; t < 32; ++t) {
    const u16* AsC = As[t & 1];
    // ---- region ph0: MFMA q0; read A23; stage A(t+1,h1)
    LGKM0();
    __builtin_amdgcn_s_setprio(1);
    MFMA_Q(aCur, 0);
    __builtin_amdgcn_s_setprio(0);
    SBAR();
#pragma unroll
    for (int e = 0; e < 2; ++e)
#pragma unroll
      for (int kb = 0; kb < 2; ++kb)
        aNxt[e][kb] = *(const bf16x8*)(AsC + aBase + (2 + e) * 1024 + slot[kb]);
    if (t + 1 < 32) stgA(t + 1, 1);
    BARRIER();
    // ---- region ph1: MFMA q1; read A45; stage B(t+2,h0)
    LGKM0();
    __builtin_amdgcn_s_setprio(1);
    MFMA_Q(aNxt, 2);
    __builtin_amdgcn_s_setprio(0);
    SBAR();
#pragma unroll
    for (int e = 0; e < 2; ++e)
#pragma unroll
      for (int kb = 0; kb < 2; ++kb)
        aCur[e][kb] = *(const bf16x8*)(AsC + aBase + (4 + e) * 1024 + slot[kb]);
    if (t + 2 < 32) stgB(t + 2, 0);
    BARRIER();
    // ---- region ph2: MFMA q2; read A67; stage B(t+2,h1); vmcnt gate for t+1
    LGKM0();
    __builtin_amdgcn_s_setprio(1);
    MFMA_Q(aCur, 4);
    __builtin_amdgcn_s_setprio(0);
    SBAR();
#pragma unroll
    for (int e = 0; e < 2; ++e)
#pragma unroll
      for (int kb = 0; kb < 2; ++kb)
        aNxt[e][kb] = *(const bf16x8*)(AsC + aBase + (6 + e) * 1024 + slot[kb]);
    if (t + 2 < 32) stgB(t + 2, 1);
    if (t < 30) { asm volatile("s_waitcnt vmcnt(4)" ::: "memory"); }
    else       { asm volatile("s_waitcnt vmcnt(0)" ::: "memory"); }
    BARRIER();
    // ---- region ph3: MFMA q3; read B(t+1)+A01(t+1); stage A(t+2,h0)
    LGKM0();
    __builtin_amdgcn_s_setprio(1);
    MFMA_Q(aNxt, 6);
    __builtin_amdgcn_s_setprio(0);
    SBAR();
    if (t + 1 < 32) {
      const u16* AsN = As[(t + 1) & 1];
      const u16* BsN = Bs[(t + 1) & 1];
#pragma unroll
      for (int ni = 0; ni < 4; ++ni)
#pragma unroll
        for (int kb = 0; kb < 2; ++kb)
          bfr[ni][kb] = *(const bf16x8*)(BsN + bBase + ni * 1024 + slot[kb]);
#pragma unroll
      for (int e = 0; e < 2; ++e)
#pragma unroll
        for (int kb = 0; kb < 2; ++kb)
          aCur[e][kb] = *(const bf16x8*)(AsN + aBase + e * 1024 + slot[kb]);
    }
    if (t + 2 < 32) stgA(t + 2, 0);
    BARRIER();
  }

  // ---------- fused epilogue: RoPE (table) + reorder, direct stores ----------
  const long crow = tileM + wm + quad * 4;
  const long ccol = tileN + wn + lrow;
  const int sec = (int)(tileN >> 11);           // 0=Q, 1=K, 2=V (uniform/block)
  const int bI = (int)(tileM >> 11);
  const int tG0 = (int)(tileM & 2047);
  if (sec < 2) {
    u16* dst = sec == 0 ? Qo : Ko;
    const float scale = sec == 0 ? 0.08838834764831845f : 1.0f;  // 1/sqrt(128)
#pragma unroll
    for (int ni = 0; ni < 4; ++ni) {
      const int col = (int)((ccol + ni * 16) & 2047);
      const int h = col >> 7, d = col & 127;
      const int i = d >> 1;                     // rope pair index
      const float2* tcol = tab + i;             // + t*64 per row
#pragma unroll
      for (int mi = 0; mi < 8; ++mi) {
        const int rowL = wm + mi * 16 + quad * 4;      // local, +r below
#pragma unroll
        for (int r = 0; r < 4; ++r) {
          const int tt = tG0 + rowL + r;
          float x = acc[mi][ni][r];
          float p = __shfl_xor(x, 1);           // partner col d^1, same row
          float2 sc = tcol[(size_t)tt * 64];    // (cos, sin), L2-hot
          float o = (x * sc.x + ((d & 1) ? p : -p) * sc.y) * scale;
          dst[(((size_t)(bI * 16 + h)) * T_ + tt) * DH + d] = f2bf(o);
        }
      }
    }
  } else {
    // V: no rope; write transposed (bh, d, t). acc[mi][ni][0..3] = 4 consec t.
#pragma unroll
    for (int ni = 0; ni < 4; ++ni) {
      const int col = (int)((ccol + ni * 16) & 2047);
      const int h = col >> 7, d = col & 127;
#pragma unroll
      for (int mi = 0; mi < 8; ++mi) {
        const int t0 = tG0 + wm + mi * 16 + quad * 4;  // 4-aligned
        ushort4 v4;
        v4.x = f2bf(acc[mi][ni][0]);
        v4.y = f2bf(acc[mi][ni][1]);
        v4.z = f2bf(acc[mi][ni][2]);
        v4.w = f2bf(acc[mi][ni][3]);
        *(ushort4*)(Vt + (((size_t)(bI * 16 + h)) * DH + d) * (size_t)T_ + t0) = v4;
      }
    }
  }
}

// ---------------- C = A (MxK) * B^T (NxK), bf16 in, bf16 or f32 out ----
// (GEMM2: N=2048 -> 512 blocks at 128^2; multiple blocks/CU resident (32KB
// LDS, 92 VGPR) so TLP hides the per-iter vmcnt(0) drain — no pipeline needed.)
__global__ __launch_bounds__(256) void gemm_bt(const u16* __restrict__ A,
                                               const u16* __restrict__ Bm,
                                               void* __restrict__ Cp,
                                               int M, int N, int K, int out_f32) {
  __shared__ u16 As[128 * 64];
  __shared__ u16 Bs[128 * 64];
  const int tid  = threadIdx.x;
  const int wave = tid >> 6, lane = tid & 63;
  const int lrow = lane & 15, quad = lane >> 4;
  const long tileM = (long)blockIdx.y * 128, tileN = (long)blockIdx.x * 128;
  const int wm = (wave >> 1) * 64, wn = (wave & 1) * 64;
  const int sRowIn = lane >> 3;
  const int sChunk = (lane & 7) ^ sRowIn;
  const int sRow0  = wave * 32 + sRowIn;
  const u16* Ag = A + (tileM + sRow0) * (long)K + sChunk * 8;
  const u16* Bg = Bm + (tileN + sRow0) * (long)K + sChunk * 8;
  u16* AsW = As + wave * 2048;
  u16* BsW = Bs + wave * 2048;
  f32x4 acc[4][4] = {};
  for (int kt = 0; kt < K; kt += 64) {
#pragma unroll
    for (int i = 0; i < 4; ++i)
      gl_lds16(Ag + kt + (size_t)i * 8 * K, AsW + i * 512);
#pragma unroll
    for (int i = 0; i < 4; ++i)
      gl_lds16(Bg + kt + (size_t)i * 8 * K, BsW + i * 512);
    __syncthreads();
#pragma unroll
    for (int kb = 0; kb < 2; ++kb) {
      const int slot8 = (((kb * 4 + quad) ^ (lrow & 7)) * 8);
      bf16x8 af[4], bfr[4];
#pragma unroll
      for (int i = 0; i < 4; ++i)
        af[i]  = *(const bf16x8*)(As + (wm + i * 16 + lrow) * 64 + slot8);
#pragma unroll
      for (int i = 0; i < 4; ++i)
        bfr[i] = *(const bf16x8*)(Bs + (wn + i * 16 + lrow) * 64 + slot8);
#pragma unroll
      for (int mi = 0; mi < 4; ++mi)
#pragma unroll
        for (int ni = 0; ni < 4; ++ni)
          acc[mi][ni] = MFMA(af[mi], bfr[ni], acc[mi][ni]);
    }
    __syncthreads();
  }
  const long crow = tileM + wm + quad * 4;
  const long ccol = tileN + wn + lrow;
  if (out_f32) {
    float* C = (float*)Cp;
#pragma unroll
    for (int mi = 0; mi < 4; ++mi)
#pragma unroll
      for (int ni = 0; ni < 4; ++ni)
#pragma unroll
        for (int r = 0; r < 4; ++r)
          C[(crow + mi * 16 + r) * (long)N + (ccol + ni * 16)] = acc[mi][ni][r];
  } else {
    u16* C = (u16*)Cp;
#pragma unroll
    for (int mi = 0; mi < 4; ++mi)
#pragma unroll
      for (int ni = 0; ni < 4; ++ni)
#pragma unroll
        for (int r = 0; r < 4; ++r)
          C[(crow + mi * 16 + r) * (long)N + (ccol + ni * 16)] = f2bf(acc[mi][ni][r]);
  }
}

// -------- causal flash attention (8-wave, 128-row q-tile, dbuf K/V) --------
// ROUND-10: reverted to the round-8 structure (best known: r9's 4-wave
// variant regressed 15us -> attn is occupancy/latency sensitive, 2 waves/SIMD
// needed) + T1 XCD-locality grid swap: launch grid (bh=32, pair=8) so the
// linearized block id = bh + 32*pair gives XCD = bh % 8 -> ALL 8 blocks
// sharing one bh's K/V (1MB) land on ONE XCD. Before: x-fastest dispatch put
// them on 8 different XCDs -> ~278MB of K/V staging re-fetched from HBM
// (~44us). After: each K/V byte is HBM-fetched once per XCD (~32MB), re-reads
// served from that XCD's L2 at ~35TB/s.
// K/V double-buffer: issue STAGE(j+1) into buf^1 before computing buf j;
// counted vmcnt(4) drains exactly tile j's 4 gl_lds; raw s_barrier (NOT
// __syncthreads - its vmcnt(0) would drain the prefetch); lgkmcnt(0) before
// the restage barrier. Pairing qtH=15-p / qtL=p -> uniform 34 K-iters.
// No-max softmax: scores bounded by construction; p = exp(s) fp32-safe.
__global__ __launch_bounds__(512) void attn_flash(const u16* __restrict__ Q,
                                                  const u16* __restrict__ K,
                                                  const u16* __restrict__ Vt,
                                                  u16* __restrict__ AO) {
  __shared__ u16 Kl[2][64 * 128];  // (key t, d), swizzle key = row&15
  __shared__ u16 Vl[2][128 * 64];  // (d, key t), swizzle key = row&7
  __shared__ u16 Pl[8 * 16 * 64];  // per-wave P staging
  const int bh = blockIdx.x;                   // 0..31  (x-fastest => co-XCD)
  const int pairIdx = blockIdx.y;              // 0..7
  const int b = bh >> 4, h = bh & 15;
  const int tid = threadIdx.x;
  const int wave = tid >> 6, lane = tid & 63;
  const int lrow = lane & 15, quad = lane >> 4;
  const u16* Qb = Q + (size_t)bh * T_ * DH;
  const u16* Kb = K + (size_t)bh * T_ * DH;
  const u16* Vb = Vt + (size_t)bh * DH * T_;

  // staging: wave stages K rows [wave*8, wave*8+8) (2 issues x 4 rows) and
  // V d-rows [wave*16, wave*16+16) (2 issues x 8 rows).
  const int kRowIn = lane >> 4;                 // 0..3
  const int vRowIn = lane >> 3;                 // 0..7
  const int vChunk = (lane & 7) ^ vRowIn;       // key = row&7 (i*8 drops out)
  u16* PlW = Pl + wave * 1024;

  // 4 gl_lds per wave per tile; order within the wave is program order, so
  // vmcnt(4) after issuing tile j+1 drains exactly tile j's 4 ops.
  auto stageKV = [&](int j, int buf) {
#pragma unroll
    for (int i = 0; i < 2; ++i) {
      int krow = wave * 8 + i * 4 + kRowIn;
      int kch = (lane & 15) ^ (krow & 15);      // staging key = row&15
      gl_lds16(Kb + (size_t)(j * 64 + krow) * DH + kch * 8,
               Kl[buf] + wave * 1024 + i * 512);
    }
#pragma unroll
    for (int i = 0; i < 2; ++i) {
      int vd = wave * 16 + i * 8 + vRowIn;
      gl_lds16(Vb + (size_t)vd * T_ + j * 64 + vChunk * 8,
               Vl[buf] + wave * 1024 + i * 512);
    }
  };

  for (int pass = 0; pass < 2; ++pass) {
    const int qt = pass == 0 ? (15 - pairIdx) : pairIdx;   // 128-row q-tile
    const int qbase = qt * 128;
    const int nkt = 2 * qt + 2;                 // K-tiles of 64

    bf16x8 qf[4];
    {
      const u16* qrow = Qb + (size_t)(qbase + wave * 16 + lrow) * DH + quad * 8;
#pragma unroll
      for (int kc = 0; kc < 4; ++kc) qf[kc] = *(const bf16x8*)(qrow + kc * 32);
    }
    f32x4 o[8] = {};
    float lsum[4] = {0.f, 0.f, 0.f, 0.f};

    stageKV(0, 0);                              // prologue prefetch

    for (int j = 0; j < nkt; ++j) {
      const int cb = j & 1;
      if (j + 1 < nkt) {
        stageKV(j + 1, cb ^ 1);                 // issue next tile early
        asm volatile("s_waitcnt vmcnt(4)" ::: "memory");  // drain tile j only
      } else {
        asm volatile("s_waitcnt vmcnt(0)" ::: "memory");
      }
      BARRIER();                                // buf[cb] ready for all waves

      const u16* KlC = Kl[cb];
      const u16* VlC = Vl[cb];
      f32x4 s[4] = {};
#pragma unroll
      for (int kc = 0; kc < 4; ++kc)
#pragma unroll
        for (int ns = 0; ns < 4; ++ns) {
          bf16x8 kf = *(const bf16x8*)(KlC + (ns * 16 + lrow) * 128 +
                                       (((kc * 4 + quad) ^ lrow) * 8));
          s[ns] = MFMA(qf[kc], kf, s[ns]);
        }
      if (j >= 2 * qt) {  // diagonal K-tiles: mask local col > local row
        const int jl = (j - 2 * qt) * 64;
#pragma unroll
        for (int ns = 0; ns < 4; ++ns)
#pragma unroll
          for (int r = 0; r < 4; ++r)
            if (jl + ns * 16 + lrow > wave * 16 + quad * 4 + r)
              s[ns][r] = -__builtin_inff();
      }
#pragma unroll
      for (int r = 0; r < 4; ++r) {
        const int prow = quad * 4 + r;
#pragma unroll
        for (int ns = 0; ns < 4; ++ns) {
          float p = __expf(s[ns][r]);           // exp(-inf) = 0 handles mask
          PlW[prow * 64 + (((ns * 2 + (lrow >> 3)) ^ (prow & 7)) * 8) +
              (lrow & 7)] = f2bf(p);
          lsum[r] += p;
        }
      }
      // no barrier: Pl is per-wave; same-wave LDS write->read ordered by lgkmcnt

#pragma unroll
      for (int kc = 0; kc < 2; ++kc) {
        bf16x8 pf = *(const bf16x8*)(PlW + lrow * 64 +
                                     (((kc * 4 + quad) ^ (lrow & 7)) * 8));
#pragma unroll
        for (int os = 0; os < 8; ++os) {
          bf16x8 vf = *(const bf16x8*)(VlC + (os * 16 + lrow) * 64 +
                                       (((kc * 4 + quad) ^ (lrow & 7)) * 8));
          o[os] = MFMA(pf, vf, o[os]);
        }
      }
      asm volatile("s_waitcnt lgkmcnt(0)" ::: "memory");  // reads of buf done
      BARRIER();                                // buf[cb] free for restage
    }
#pragma unroll
    for (int r = 0; r < 4; ++r) {
      lsum[r] += __shfl_xor(lsum[r], 1, 16);
      lsum[r] += __shfl_xor(lsum[r], 2, 16);
      lsum[r] += __shfl_xor(lsum[r], 4, 16);
      lsum[r] += __shfl_xor(lsum[r], 8, 16);
    }
#pragma unroll
    for (int r = 0; r < 4; ++r) {
      float inv = 1.0f / lsum[r];
      const size_t row = (size_t)b * T_ + qbase + wave * 16 + quad * 4 + r;
      u16* dst = AO + row * DM + h * DH;
#pragma unroll
      for (int os = 0; os < 8; ++os) dst[os * 16 + lrow] = f2bf(o[os][r] * inv);
    }
  }
}

extern "C" void kernel_launch(void* const* d_in, const int* in_sizes, int n_in,
                              void* d_out, int out_size, void* d_ws, size_t ws_size,
                              hipStream_t stream) {
  const float* x    = (const float*)d_in[0];
  const float* Wqkv = (const float*)d_in[1];
  const float* WO   = (const float*)d_in[2];
  char* ws = (char*)d_ws;
  size_t off = 0;
  u16* xb   = (u16*)(ws + off); off += (size_t)B_ * T_ * DM * 2;        // 16.8MB
  u16* wqb  = (u16*)(ws + off); off += (size_t)NQKV * DM * 2;           // 25.2MB
  u16* wob  = (u16*)(ws + off); off += (size_t)DM * DM * 2;             // 8.4MB
  u16* Qb   = (u16*)(ws + off); off += (size_t)B_ * NH * T_ * DH * 2;   // 16.8MB
  u16* Kb   = (u16*)(ws + off); off += (size_t)B_ * NH * T_ * DH * 2;
  u16* Vtb  = (u16*)(ws + off); off += (size_t)B_ * NH * T_ * DH * 2;
  float2* tabp = (float2*)(ws + off); off += (size_t)T_ * 64 * 8;       // 1MB
  u16* AO   = xb;  // alias: xb dead after GEMM1, AO written after

  const int nc = (B_ * T_ * DM + NQKV * DM + DM * DM) / 4;
  cast3<<<(nc + 255) / 256, 256, 0, stream>>>(x, xb, Wqkv, wqb, WO, wob, tabp);

  gemm1_8ph<<<dim3(G1_N / 256, G1_M / 256), 512, 0, stream>>>(xb, wqb, tabp,
                                                              Qb, Kb, Vtb);

  // grid (bh, pair): linear id = bh + 32*pair -> XCD = bh%8; all 8 blocks of
  // one bh co-resident on one XCD -> K/V staging L2-local (T1).
  attn_flash<<<dim3(B_ * NH, 8), 512, 0, stream>>>(Qb, Kb, Vtb, AO);

  gemm_bt<<<dim3(DM / 128, B_ * T_ / 128), 256, 0, stream>>>(
      AO, wob, d_out, B_ * T_, DM, DM, 1);
}